// Round 8
// baseline (369.435 us; speedup 1.0000x reference)
//
#include <hip/hip_runtime.h>

namespace {
constexpr int kBB = 64, kH = 64, kW = 64, kC = 128, kP = 64;
constexpr int kHW = kH * kW;                 // 4096
constexpr long kRows = (long)kBB * kHW;      // 262144
constexpr long kOutElems = kRows * kC;       // 33554432

constexpr int kGemmTiles = (int)(kRows / 64); // 4096 tiles of 64 rows
constexpr int kZBlocks = 512;                 // each reduces 512 z rows
constexpr int kGrid = kGemmTiles + kZBlocks;  // 4608, interleaved 8:1 by bid%9

typedef float f4 __attribute__((ext_vector_type(4)));

// Async global->LDS DMA, 16 B per lane. Side-effecting intrinsic: the compiler
// can neither sink nor elide it (round 7's register "prefetch" was sunk —
// VGPR=44 proved the loads moved to their use point). LDS dest must be linear
// in lane (ours is: dest = base + t, 16 B each).
__device__ __forceinline__ void dma16(const f4* g, f4* l) {
  __builtin_amdgcn_global_load_lds(
      (const __attribute__((address_space(1))) unsigned int*)g,
      (__attribute__((address_space(3))) unsigned int*)l, 16, 0, 0);
}

// Block-specialized fused kernel with a true async k-pipeline.
//   GEMM blocks (bid%9 != 8): out[64r][128c] = s_tile * k.
//     LDS = k quarter double-buffer 2x8 KB + s 16 KB = exactly 32 KB
//     (5 blocks/CU). Per quarter: issue DMA for quarter q+1 into buf^1,
//     compute 512 FMAs on buf, then vmcnt(0)+barrier — DMA latency hides
//     under the FMAs *within* each wave (T3-lite 2-phase pipeline).
//   z blocks (bid%9 == 8): pure 512-row streaming reduction; LDS overlaid
//     (red on s_lds, qred on kb).
__global__ __launch_bounds__(256) void fused_kernel(const float* __restrict__ z,
                                                    const float* __restrict__ s,
                                                    const float* __restrict__ kmat,
                                                    float* __restrict__ out,
                                                    float* __restrict__ zsum,
                                                    float* __restrict__ z2) {
  __shared__ f4 kb[2][16][kC / 4];   // 2 x 8 KB: k quarters (16 p-rows each)
  __shared__ f4 s_lds[64][kP / 4];   // 16 KB   (z path: red buffer)

  const int t = threadIdx.x;
  const int cq = t & 31;   // float4-column 0..31
  const int tg = t >> 5;   // row-group 0..7
  const int bid = blockIdx.x;
  const int r9 = bid % 9;

  if (r9 == 8) {
    // ================= z-reduction block: 512 rows, one batch image ==========
    const int zi = bid / 9;                  // 0..511
    const long row0 = (long)zi * 512;
    const int b = (int)(row0 >> 12);         // 8 z-blocks per image
    const f4* z4 = reinterpret_cast<const f4*>(z + row0 * kC);

    f4 sum = (f4){0.f, 0.f, 0.f, 0.f};
    float q = 0.f;
#pragma unroll 8
    for (int i = 0; i < 64; ++i) {           // rows tg + 8*i
      const f4 v = __builtin_nontemporal_load(&z4[((long)(tg + 8 * i)) * 32 + cq]);
      sum += v;
      q += v.x * v.x + v.y * v.y + v.z * v.z + v.w * v.w;
    }

    f4* red = &s_lds[0][0];                  // 256 f4 = 4 KB
    float* qred = reinterpret_cast<float*>(&kb[0][0][0]);  // kb unused on z path
    red[tg * 32 + cq] = sum;
    for (int off = 32; off > 0; off >>= 1) q += __shfl_down(q, off, 64);
    if ((t & 63) == 0) qred[t >> 6] = q;
    __syncthreads();

    if (tg == 0) {
      f4 tot = red[cq];
#pragma unroll
      for (int j = 1; j < 8; ++j) tot += red[j * 32 + cq];
      atomicAdd(&zsum[b * kC + cq * 4 + 0], tot.x);
      atomicAdd(&zsum[b * kC + cq * 4 + 1], tot.y);
      atomicAdd(&zsum[b * kC + cq * 4 + 2], tot.z);
      atomicAdd(&zsum[b * kC + cq * 4 + 3], tot.w);
      if (cq == 0) atomicAdd(&z2[b], qred[0] + qred[1] + qred[2] + qred[3]);
    }
    return;
  }

  // ================= GEMM block: one 64-row tile ==============================
  const long tile = (long)(bid / 9) * 8 + r9;    // 0..4095
  const long rowbase = tile * 64;

  const f4* k4g = reinterpret_cast<const f4*>(kmat);            // k4g[p*32+col]
  const f4* s4 = reinterpret_cast<const f4*>(s + rowbase * kP); // 1024 f4
  f4* s_flat = &s_lds[0][0];
  f4* kb0 = &kb[0][0][0];
  f4* kb1 = &kb[1][0][0];

  // ---- DMA stage: s tile (4 chunks) + k quarter 0 (2 chunks) ----
#pragma unroll
  for (int i = 0; i < 4; ++i) dma16(&s4[t + 256 * i], &s_flat[t + 256 * i]);
#pragma unroll
  for (int i = 0; i < 2; ++i) dma16(&k4g[t + 256 * i], &kb0[t + 256 * i]);
  asm volatile("s_waitcnt vmcnt(0)" ::: "memory");
  __syncthreads();

  f4 acc[8];
#pragma unroll
  for (int j = 0; j < 8; ++j) acc[j] = (f4){0.f, 0.f, 0.f, 0.f};

#pragma unroll
  for (int q = 0; q < 4; ++q) {
    f4* kc = (q & 1) ? kb1 : kb0;
    if (q < 3) {  // issue next quarter's DMA before this quarter's compute
      f4* kn = (q & 1) ? kb0 : kb1;
#pragma unroll
      for (int i = 0; i < 2; ++i)
        dma16(&k4g[512 * (q + 1) + t + 256 * i], &kn[t + 256 * i]);
    }

#pragma unroll
    for (int pc4 = 0; pc4 < 4; ++pc4) {      // p in chunks of 4
      const int pcg = 4 * q + pc4;           // s float4-column 0..15
      const f4 k0 = kc[(4 * pc4 + 0) * 32 + cq];
      const f4 k1 = kc[(4 * pc4 + 1) * 32 + cq];
      const f4 k2 = kc[(4 * pc4 + 2) * 32 + cq];
      const f4 k3 = kc[(4 * pc4 + 3) * 32 + cq];
#pragma unroll
      for (int j = 0; j < 8; ++j) {
        const f4 sv = s_lds[tg + 8 * j][pcg];  // LDS broadcast across 32 lanes
        acc[j].x += sv.x * k0.x + sv.y * k1.x + sv.z * k2.x + sv.w * k3.x;
        acc[j].y += sv.x * k0.y + sv.y * k1.y + sv.z * k2.y + sv.w * k3.y;
        acc[j].z += sv.x * k0.z + sv.y * k1.z + sv.z * k2.z + sv.w * k3.z;
        acc[j].w += sv.x * k0.w + sv.y * k1.w + sv.z * k2.w + sv.w * k3.w;
      }
    }

    if (q < 3) {  // next quarter's DMA had ~1000 FMA-cycles to land
      asm volatile("s_waitcnt vmcnt(0)" ::: "memory");
      __syncthreads();
    }
  }

  f4* out4 = reinterpret_cast<f4*>(out + rowbase * kC);
#pragma unroll
  for (int j = 0; j < 8; ++j)
    __builtin_nontemporal_store(acc[j], &out4[(tg + 8 * j) * 32 + cq]);
}

// distance[b][p] = z2[b] - 2*dot(zsum[b],k[p]) + 4096*||k[p]||^2
__global__ __launch_bounds__(256) void dist_kernel(const float* __restrict__ zsum,
                                                   const float* __restrict__ z2,
                                                   const float* __restrict__ kmat,
                                                   float* __restrict__ dist) {
  const int g = blockIdx.x * 256 + threadIdx.x;  // 0..4095
  const int b = g >> 6;
  const int p = g & 63;
  const f4* zs4 = reinterpret_cast<const f4*>(zsum + b * kC);
  const f4* k4 = reinterpret_cast<const f4*>(kmat + p * kC);
  float dot = 0.f, k2 = 0.f;
#pragma unroll 8
  for (int i = 0; i < kC / 4; ++i) {
    const f4 kk = k4[i];
    const f4 zz = zs4[i];
    dot += zz.x * kk.x + zz.y * kk.y + zz.z * kk.z + zz.w * kk.w;
    k2 += kk.x * kk.x + kk.y * kk.y + kk.z * kk.z + kk.w * kk.w;
  }
  dist[g] = z2[b] - 2.f * dot + (float)kHW * k2;
}

}  // namespace

extern "C" void kernel_launch(void* const* d_in, const int* in_sizes, int n_in,
                              void* d_out, int out_size, void* d_ws, size_t ws_size,
                              hipStream_t stream) {
  const float* z = (const float*)d_in[0];      // (64,64,64,128)
  const float* s = (const float*)d_in[1];      // (64,64,64,64)
  const float* kmat = (const float*)d_in[2];   // (64,1,1,128)

  float* out = (float*)d_out;                  // 33554432 floats
  float* dist = out + kOutElems;               // 4096 floats

  float* zsum = (float*)d_ws;                  // 64*128 floats
  float* z2 = zsum + kBB * kC;                 // 64 floats

  // zero the atomic accumulators (ws is poisoned 0xAA each call)
  (void)hipMemsetAsync(d_ws, 0, (size_t)(kBB * kC + kBB) * sizeof(float), stream);

  fused_kernel<<<kGrid, 256, 0, stream>>>(z, s, kmat, out, zsum, z2);
  dist_kernel<<<16, 256, 0, stream>>>(zsum, z2, kmat, dist);
}

// Round 9
// 284.724 us; speedup vs baseline: 1.2975x; 1.2975x over previous
//
#include <hip/hip_runtime.h>

namespace {
constexpr int kBB = 64, kH = 64, kW = 64, kC = 128, kP = 64;
constexpr int kHW = kH * kW;                 // 4096
constexpr long kRows = (long)kBB * kHW;      // 262144
constexpr long kOutElems = kRows * kC;       // 33554432

constexpr int kGemmTiles = (int)(kRows / 128); // 2048 tiles of 128 rows
constexpr int kZBlocks = 512;                  // each reduces 512 z rows
constexpr int kGrid = kGemmTiles + kZBlocks;   // 2560, interleaved 4:1 by bid%5

typedef float f4 __attribute__((ext_vector_type(4)));

// Round-9: DS-pipe theory. Rounds 5-7 pinned at 92-95 us across three
// structures with VALU~50%, HBM~40%, conflicts 0, occupancy 17->35% (no
// effect): the saturated resource is the LDS data pipe (12 ds_read_b128 per
// thread per pc = ~50-60 us/CU, > 27 us FMA floor, invisible in counters).
// Fix: 2-column register tiling — each thread owns 8 rows x 2 f4-cols
// (cq2, cq2+16), so per pc it reads 8 k + 8 s b128 for 2x the FMAs:
// 1.5x fewer DS instructions per output element. 16 B lane stride kept
// (proven 0-conflict). Block = 128-row tile; k staged in halves (16 KB)
// so LDS = 16+32 = 48 KB -> 3 blocks/CU.
__global__ __launch_bounds__(256) void fused_kernel(const float* __restrict__ z,
                                                    const float* __restrict__ s,
                                                    const float* __restrict__ kmat,
                                                    float* __restrict__ out,
                                                    float* __restrict__ zsum,
                                                    float* __restrict__ z2) {
  __shared__ f4 k_lds[32][kC / 4];    // 16 KB — one half of k (32 p-rows)
  __shared__ f4 s_lds[128][kP / 4];   // 32 KB — s tile (z path: red buffer)

  const int t = threadIdx.x;
  const int bid = blockIdx.x;
  const int r5 = bid % 5;

  if (r5 == 4) {
    // ================= z-reduction block: 512 rows, one batch image ==========
    const int cq = t & 31;
    const int tg = t >> 5;
    const int zi = bid / 5;                  // 0..511
    const long row0 = (long)zi * 512;
    const int b = (int)(row0 >> 12);         // 8 z-blocks per image
    const f4* z4 = reinterpret_cast<const f4*>(z + row0 * kC);

    f4 sum = (f4){0.f, 0.f, 0.f, 0.f};
    float q = 0.f;
#pragma unroll 8
    for (int i = 0; i < 64; ++i) {           // rows tg + 8*i
      const f4 v = __builtin_nontemporal_load(&z4[((long)(tg + 8 * i)) * 32 + cq]);
      sum += v;
      q += v.x * v.x + v.y * v.y + v.z * v.z + v.w * v.w;
    }

    f4* red = &s_lds[0][0];                  // 256 f4 = 4 KB
    float* qred = reinterpret_cast<float*>(&k_lds[0][0]);  // k_lds unused here
    red[tg * 32 + cq] = sum;
    for (int off = 32; off > 0; off >>= 1) q += __shfl_down(q, off, 64);
    if ((t & 63) == 0) qred[t >> 6] = q;
    __syncthreads();

    if (tg == 0) {
      f4 tot = red[cq];
#pragma unroll
      for (int j = 1; j < 8; ++j) tot += red[j * 32 + cq];
      atomicAdd(&zsum[b * kC + cq * 4 + 0], tot.x);
      atomicAdd(&zsum[b * kC + cq * 4 + 1], tot.y);
      atomicAdd(&zsum[b * kC + cq * 4 + 2], tot.z);
      atomicAdd(&zsum[b * kC + cq * 4 + 3], tot.w);
      if (cq == 0) atomicAdd(&z2[b], qred[0] + qred[1] + qred[2] + qred[3]);
    }
    return;
  }

  // ================= GEMM block: one 128-row tile =============================
  const int cq2 = t & 15;   // col-pair id: owns f4-cols cq2 and cq2+16
  const int tg = t >> 4;    // row-group 0..15; owns rows tg + 16*j
  const long tile = (long)(bid / 5) * 4 + r5;    // 0..2047
  const long rowbase = tile * 128;

  // stage k first half (p=0..31, 16 KB; L2-resident after first touch)
  const f4* k4g = reinterpret_cast<const f4*>(kmat);
  f4* k_flat = &k_lds[0][0];
#pragma unroll
  for (int i = 0; i < 4; ++i) k_flat[t + 256 * i] = k4g[t + 256 * i];

  // stage s tile (32 KB, read-once -> nontemporal)
  const f4* s4 = reinterpret_cast<const f4*>(s + rowbase * kP);
  f4* s_flat = &s_lds[0][0];
#pragma unroll
  for (int i = 0; i < 8; ++i)
    s_flat[t + 256 * i] = __builtin_nontemporal_load(&s4[t + 256 * i]);

  // prefetch k second half into regs (compiler may sink it; harmless)
  f4 kpre[4];
#pragma unroll
  for (int i = 0; i < 4; ++i) kpre[i] = k4g[1024 + t + 256 * i];

  __syncthreads();  // k-half-1 + s staged

  f4 acc0[8], acc1[8];
#pragma unroll
  for (int j = 0; j < 8; ++j) {
    acc0[j] = (f4){0.f, 0.f, 0.f, 0.f};
    acc1[j] = (f4){0.f, 0.f, 0.f, 0.f};
  }

  // ---- GEMM-A: p = 0..31 ----
#pragma unroll 2
  for (int pc = 0; pc < 8; ++pc) {  // p in chunks of 4
    const f4 ka0 = k_lds[4 * pc + 0][cq2];
    const f4 ka1 = k_lds[4 * pc + 1][cq2];
    const f4 ka2 = k_lds[4 * pc + 2][cq2];
    const f4 ka3 = k_lds[4 * pc + 3][cq2];
    const f4 kb0 = k_lds[4 * pc + 0][cq2 + 16];
    const f4 kb1 = k_lds[4 * pc + 1][cq2 + 16];
    const f4 kb2 = k_lds[4 * pc + 2][cq2 + 16];
    const f4 kb3 = k_lds[4 * pc + 3][cq2 + 16];
#pragma unroll
    for (int j = 0; j < 8; ++j) {
      const f4 sv = s_lds[tg + 16 * j][pc];  // broadcast across 16 lanes
      acc0[j].x += sv.x * ka0.x + sv.y * ka1.x + sv.z * ka2.x + sv.w * ka3.x;
      acc0[j].y += sv.x * ka0.y + sv.y * ka1.y + sv.z * ka2.y + sv.w * ka3.y;
      acc0[j].z += sv.x * ka0.z + sv.y * ka1.z + sv.z * ka2.z + sv.w * ka3.z;
      acc0[j].w += sv.x * ka0.w + sv.y * ka1.w + sv.z * ka2.w + sv.w * ka3.w;
      acc1[j].x += sv.x * kb0.x + sv.y * kb1.x + sv.z * kb2.x + sv.w * kb3.x;
      acc1[j].y += sv.x * kb0.y + sv.y * kb1.y + sv.z * kb2.y + sv.w * kb3.y;
      acc1[j].z += sv.x * kb0.z + sv.y * kb1.z + sv.z * kb2.z + sv.w * kb3.z;
      acc1[j].w += sv.x * kb0.w + sv.y * kb1.w + sv.z * kb2.w + sv.w * kb3.w;
    }
  }

  __syncthreads();  // everyone done reading k half 1
#pragma unroll
  for (int i = 0; i < 4; ++i) k_flat[t + 256 * i] = kpre[i];
  __syncthreads();  // k half 2 visible

  // ---- GEMM-B: p = 32..63 (s f4-col pc = 8..15) ----
#pragma unroll 2
  for (int pc = 8; pc < 16; ++pc) {
    const f4 ka0 = k_lds[4 * (pc - 8) + 0][cq2];
    const f4 ka1 = k_lds[4 * (pc - 8) + 1][cq2];
    const f4 ka2 = k_lds[4 * (pc - 8) + 2][cq2];
    const f4 ka3 = k_lds[4 * (pc - 8) + 3][cq2];
    const f4 kb0 = k_lds[4 * (pc - 8) + 0][cq2 + 16];
    const f4 kb1 = k_lds[4 * (pc - 8) + 1][cq2 + 16];
    const f4 kb2 = k_lds[4 * (pc - 8) + 2][cq2 + 16];
    const f4 kb3 = k_lds[4 * (pc - 8) + 3][cq2 + 16];
#pragma unroll
    for (int j = 0; j < 8; ++j) {
      const f4 sv = s_lds[tg + 16 * j][pc];
      acc0[j].x += sv.x * ka0.x + sv.y * ka1.x + sv.z * ka2.x + sv.w * ka3.x;
      acc0[j].y += sv.x * ka0.y + sv.y * ka1.y + sv.z * ka2.y + sv.w * ka3.y;
      acc0[j].z += sv.x * ka0.z + sv.y * ka1.z + sv.z * ka2.z + sv.w * ka3.z;
      acc0[j].w += sv.x * ka0.w + sv.y * ka1.w + sv.z * ka2.w + sv.w * ka3.w;
      acc1[j].x += sv.x * kb0.x + sv.y * kb1.x + sv.z * kb2.x + sv.w * kb3.x;
      acc1[j].y += sv.x * kb0.y + sv.y * kb1.y + sv.z * kb2.y + sv.w * kb3.y;
      acc1[j].z += sv.x * kb0.z + sv.y * kb1.z + sv.z * kb2.z + sv.w * kb3.z;
      acc1[j].w += sv.x * kb0.w + sv.y * kb1.w + sv.z * kb2.w + sv.w * kb3.w;
    }
  }

  f4* out4 = reinterpret_cast<f4*>(out + rowbase * kC);
#pragma unroll
  for (int j = 0; j < 8; ++j) {
    const long r = tg + 16 * j;
    __builtin_nontemporal_store(acc0[j], &out4[r * 32 + cq2]);
    __builtin_nontemporal_store(acc1[j], &out4[r * 32 + cq2 + 16]);
  }
}

// distance[b][p] = z2[b] - 2*dot(zsum[b],k[p]) + 4096*||k[p]||^2
__global__ __launch_bounds__(256) void dist_kernel(const float* __restrict__ zsum,
                                                   const float* __restrict__ z2,
                                                   const float* __restrict__ kmat,
                                                   float* __restrict__ dist) {
  const int g = blockIdx.x * 256 + threadIdx.x;  // 0..4095
  const int b = g >> 6;
  const int p = g & 63;
  const f4* zs4 = reinterpret_cast<const f4*>(zsum + b * kC);
  const f4* k4 = reinterpret_cast<const f4*>(kmat + p * kC);
  float dot = 0.f, k2 = 0.f;
#pragma unroll 8
  for (int i = 0; i < kC / 4; ++i) {
    const f4 kk = k4[i];
    const f4 zz = zs4[i];
    dot += zz.x * kk.x + zz.y * kk.y + zz.z * kk.z + zz.w * kk.w;
    k2 += kk.x * kk.x + kk.y * kk.y + kk.z * kk.z + kk.w * kk.w;
  }
  dist[g] = z2[b] - 2.f * dot + (float)kHW * k2;
}

}  // namespace

extern "C" void kernel_launch(void* const* d_in, const int* in_sizes, int n_in,
                              void* d_out, int out_size, void* d_ws, size_t ws_size,
                              hipStream_t stream) {
  const float* z = (const float*)d_in[0];      // (64,64,64,128)
  const float* s = (const float*)d_in[1];      // (64,64,64,64)
  const float* kmat = (const float*)d_in[2];   // (64,1,1,128)

  float* out = (float*)d_out;                  // 33554432 floats
  float* dist = out + kOutElems;               // 4096 floats

  float* zsum = (float*)d_ws;                  // 64*128 floats
  float* z2 = zsum + kBB * kC;                 // 64 floats

  // zero the atomic accumulators (ws is poisoned 0xAA each call)
  (void)hipMemsetAsync(d_ws, 0, (size_t)(kBB * kC + kBB) * sizeof(float), stream);

  fused_kernel<<<kGrid, 256, 0, stream>>>(z, s, kmat, out, zsum, z2);
  dist_kernel<<<16, 256, 0, stream>>>(zsum, z2, kmat, dist);
}